// Round 9
// baseline (26.501 us; speedup 1.0000x reference)
//
#include <hip/hip_runtime.h>
#include <math.h>

// Voxelized chamfer via bf16 MFMA with algebra folded into unused K-slots:
//   vox coords are integer-valued fp32, |v| <= ~160 -> EXACT in bf16.
//   A row i : {-2qx, -2qy, -2qz, 1, 1, 0...}   (-2q = exponent shift, exact)
//   B col j : { cx,   cy,   cz, yh, yl, 0...}  (yy = yh+yl exact bf16 split)
//   MFMA   -> yy_j - 2 q_i.c_j  directly (all |vals| < 2^24: fp32-exact).
//   row-min_j (that) + xx_i = chamfer row-min. Epilogue = 1 min3 / 2 evals.
//   loss = mean(row-mins, pred->gt) + mean(row-mins, gt->pred).
//
// k0: pack pass — voxelize all 32768 points ONCE (all IEEE divides here,
//     bit-identical to reference), emit per point: B-frag int4, A-frag int4,
//     fp32 norm. Kills the 64x-redundant per-block voxelize work of R8.
// k1: 512 blocks = (dir, batch, 64-query tile). Candidate staging is now a
//     pure int4 copy, done in TWO 2048-point halves (32 KB LDS -> 4 blocks/
//     CU, double the waves/SIMD of R8 for latency hiding). Main loop per
//     wave-half: 16 pairs x (2 ds_read_b128 + 8 MFMA + 16 min3). Row-min
//     wrap-up: 4-level shfl min, +xx, cross-wave LDS min, exact int sum ->
//     partials[bid] (1 float per block, no intermediates).
// k2: 1 block sums 512 partials (fixed-order tree, exact) and OVERWRITES
//     out[0] = sum * 2^-14. No init dispatch, no atomics, deterministic.
//
// Exactness: yy <= ~3*160^2 < 2^17; yh = 256*floor(yy/256) (multiplier has
// <=9 sig bits -> bf16-exact), yl in [0,256) integer -> bf16-exact; -2q even
// |.| <= 512 -> bf16-exact. MFMA products <= ~2^17, 5-term fp32 accum exact.

typedef float  f32x4  __attribute__((ext_vector_type(4)));
typedef short  bf16x8 __attribute__((ext_vector_type(8)));

constexpr int NPTS  = 4096;
constexpr int BLK   = 256;
constexpr int QPB   = 64;             // query rows per block
constexpr int NTB   = NPTS / QPB;     // 64 row tiles per (dir, batch)
constexpr int BATCH = 4;
constexpr int HALF  = 2048;           // candidates staged per half
constexpr float FINF  = 3.402823466e38f;
constexpr float SCALE = 1.0f / 16384.0f;   // 1/(B*N) = 2^-14, exact

__device__ __forceinline__ float vox(float c, float off) {
    return truncf((c + off) / 0.05f);  // IEEE div: bit-matches reference
}
__device__ __forceinline__ unsigned bfbits(float v) {
    return __float_as_uint(v) >> 16;   // exact for the value classes above
}
__device__ __forceinline__ float min3(float a, float b, float c) {
    return fminf(fminf(a, b), c);      // clang fuses to v_min3_f32
}

// ---------------- k0: one-shot voxelize + fragment pack ----------------
__global__ __launch_bounds__(BLK) void pack_kernel(
    const float* __restrict__ preds, const float* __restrict__ gts,
    int4* __restrict__ bfragG,        // [2*BATCH*NPTS]
    int4* __restrict__ afragG,        // [2*BATCH*NPTS]
    float* __restrict__ xxG)          // [2*BATCH*NPTS]
{
    constexpr unsigned ONE = 0x3F80u;   // bf16 1.0
    const int gid   = blockIdx.x * BLK + threadIdx.x;   // 0..32767
    const int cloud = gid >> 14;                        // 0: preds, 1: gts
    const int idx   = gid & 16383;                      // b*NPTS + i
    const float* __restrict__ src = (cloud ? gts : preds) + (size_t)idx * 3;

    const float x = vox(src[0], 3.0f);
    const float y = vox(src[1], 3.0f);
    const float z = vox(src[2], 1.0f);
    const float yy = fmaf(z, z, fmaf(y, y, x * x));      // exact int
    const float hi = floorf(yy * 0.00390625f) * 256.0f;  // exact
    const float lo = yy - hi;                            // in [0,256)

    bfragG[gid] = make_int4(
        (int)((bfbits(y) << 16) | bfbits(x)),            // k0:cx k1:cy
        (int)((bfbits(hi) << 16) | bfbits(z)),           // k2:cz k3:yh
        (int)(bfbits(lo)),                               // k4:yl k5:0
        0);
    const float mx = -2.0f * x, my = -2.0f * y, mz = -2.0f * z;  // exact
    afragG[gid] = make_int4(
        (int)((bfbits(my) << 16) | bfbits(mx)),          // k0 k1
        (int)((ONE << 16) | bfbits(mz)),                 // k2 k3:1
        (int)(ONE),                                      // k4:1 k5:0
        0);
    xxG[gid] = yy;
}

// ---------------- k1: main chamfer row-min pass ----------------
__global__ __launch_bounds__(BLK) void chamfer_rows_kernel(
    const int4* __restrict__ bfragG,
    const int4* __restrict__ afragG,
    const float* __restrict__ xxG,
    float* __restrict__ partials)      // [512]
{
    __shared__ int4  cfrag[HALF];      // 32 KB -> 4 blocks/CU
    __shared__ float qxxS[QPB];
    __shared__ float waveRow[4][QPB];

    const int t    = threadIdx.x;
    const int bid  = blockIdx.x;        // dir*256 + b*64 + tile
    const int dir  = bid >> 8;
    const int rem  = bid & 255;
    const int b    = rem >> 6;
    const int tile = rem & 63;
    const int w    = t >> 6;
    const int lane = t & 63;
    const int lq   = lane & 15;
    const int grp  = lane >> 4;
    const bool lo_g = (grp == 0);       // k=0..7 carrier group

    const int qoff = dir * (BATCH * NPTS) + b * NPTS + tile * QPB;
    const int coff = (1 - dir) * (BATCH * NPTS) + b * NPTS;

    // A fragments straight from global (L1/L2-hot after k0).
    bf16x8 afrag[4];
    #pragma unroll
    for (int rt = 0; rt < 4; ++rt) {
        const int4 qv = afragG[qoff + rt * 16 + lq];
        int4 ai = { lo_g ? qv.x : 0, lo_g ? qv.y : 0, lo_g ? qv.z : 0, 0 };
        afrag[rt] = __builtin_bit_cast(bf16x8, ai);
    }
    if (t < QPB) qxxS[t] = xxG[qoff + t];

    f32x4 rm[4];
    #pragma unroll
    for (int rt = 0; rt < 4; ++rt) rm[rt] = (f32x4){FINF, FINF, FINF, FINF};
    const f32x4 zero = (f32x4){0.f, 0.f, 0.f, 0.f};

    // ---- two candidate halves: copy-stage 32 KB, then scan ----
    #pragma unroll 1
    for (int h = 0; h < 2; ++h) {
        __syncthreads();                       // prev-half readers done
        const int4* __restrict__ srcH = bfragG + coff + h * HALF;
        #pragma unroll
        for (int k = 0; k < HALF / BLK; ++k)   // 8 int4 per thread
            cfrag[k * BLK + t] = srcH[k * BLK + t];
        __syncthreads();

        #pragma unroll 2
        for (int jp = w * 16; jp < w * 16 + 16; ++jp) {
            const int jA = jp * 2, jB = jA + 1;
            const int4 bva = cfrag[jA * 16 + lq];   // b128, 4-way broadcast
            const int4 bvb = cfrag[jB * 16 + lq];
            const bf16x8 bfa = __builtin_bit_cast(bf16x8, bva);
            const bf16x8 bfb = __builtin_bit_cast(bf16x8, bvb);

            f32x4 dA[4], dB[4];
            #pragma unroll
            for (int rt = 0; rt < 4; ++rt)
                dA[rt] = __builtin_amdgcn_mfma_f32_16x16x32_bf16(
                    afrag[rt], bfa, zero, 0, 0, 0);
            #pragma unroll
            for (int rt = 0; rt < 4; ++rt)
                dB[rt] = __builtin_amdgcn_mfma_f32_16x16x32_bf16(
                    afrag[rt], bfb, zero, 0, 0, 0);
            #pragma unroll
            for (int rt = 0; rt < 4; ++rt) {
                #pragma unroll
                for (int i = 0; i < 4; ++i)
                    rm[rt][i] = min3(rm[rt][i], dA[rt][i], dB[rt][i]);
            }
        }
    }

    // ---- row-min wrap-up: min over the 16 cols held across lq lanes ----
    #pragma unroll
    for (int rt = 0; rt < 4; ++rt) {
        #pragma unroll
        for (int i = 0; i < 4; ++i) {
            float v = rm[rt][i];
            v = fminf(v, __shfl_xor(v, 1, 64));
            v = fminf(v, __shfl_xor(v, 2, 64));
            v = fminf(v, __shfl_xor(v, 4, 64));
            v = fminf(v, __shfl_xor(v, 8, 64));
            const int r = rt * 16 + grp * 4 + i;   // C/D row map (m89/m91)
            if (lq == 0) waveRow[w][r] = v + qxxS[r];
        }
    }
    __syncthreads();

    if (w == 0) {                       // lane r owns query row r
        float v = fminf(fminf(waveRow[0][lane], waveRow[1][lane]),
                        fminf(waveRow[2][lane], waveRow[3][lane]));
        #pragma unroll
        for (int o = 32; o >= 1; o >>= 1) v += __shfl_xor(v, o, 64);
        if (lane == 0) partials[bid] = v;   // exact int sum of 64 row-mins
    }
}

// ---------------- k2: tiny fixed-order final reduce ----------------
__global__ __launch_bounds__(BLK) void chamfer_finish_kernel(
    const float* __restrict__ partials, float* __restrict__ out)
{
    __shared__ float s1[BLK];
    const int t = threadIdx.x;
    s1[t] = partials[t] + partials[t + 256];
    __syncthreads();
    for (int k = 128; k > 0; k >>= 1) {
        if (t < k) s1[t] += s1[t + k];
        __syncthreads();
    }
    if (t == 0) out[0] = s1[0] * SCALE;    // overwrite: no init needed
}

extern "C" void kernel_launch(void* const* d_in, const int* in_sizes, int n_in,
                              void* d_out, int out_size, void* d_ws, size_t ws_size,
                              hipStream_t stream)
{
    const float* preds = (const float*)d_in[0];
    const float* gts   = (const float*)d_in[1];
    float* out = (float*)d_out;

    const int NPT = 2 * BATCH * NPTS;                  // 32768 points
    int4*  bfragG = (int4*)d_ws;                       // 512 KB
    int4*  afragG = bfragG + NPT;                      // 512 KB
    float* xxG    = (float*)(afragG + NPT);            // 128 KB
    float* partials = xxG + NPT;                       // 2 KB

    pack_kernel<<<NPT / BLK, BLK, 0, stream>>>(preds, gts, bfragG, afragG, xxG);
    chamfer_rows_kernel<<<2 * BATCH * NTB, BLK, 0, stream>>>(
        bfragG, afragG, xxG, partials);
    chamfer_finish_kernel<<<1, BLK, 0, stream>>>(partials, out);
}